// Round 7
// baseline (511.156 us; speedup 1.0000x reference)
//
#include <hip/hip_runtime.h>
#include <cstddef>
#include <cstdint>

// EdgeNet bf16-MFMA pipeline, round 7:
//   AB[n] precomputed per node (A = x@W0i^T - pos@W0e^T + b0 | B = x@W0j^T + pos@W0e^T)
//   Edge kernel: persistent 512 blocks x 512 thr (8 waves), BM=64.
//   Cross-tile VGPR prefetch (32 regs/thread) + RAW barriers (lgkmcnt only,
//   vmcnt kept flying) -> gather latency hidden under layer1/2 MFMA.
//   8-way dup-free weight tiling; separate h1/h2 LDS; 2 barriers/tile.

#define N_NODES_C 50000
#define N_EDGES_C 800000
#define D_FEAT_C  128
#define IN_CH_C   259
#define HID_C     256
#define OUT_CH_C  128

#define BM7    64
#define NT7    (N_EDGES_C / BM7)   // 12500
#define GRID7  512
#define HSTR7  264                  // u16 row stride (528B, 16B-aligned)

typedef unsigned short u16;
typedef short bf16x8 __attribute__((ext_vector_type(8)));
typedef float f32x4 __attribute__((ext_vector_type(4)));

__device__ __forceinline__ u16 f2bf(float f) {
    union { float f; unsigned u; } v; v.f = f;
    unsigned u = v.u;
    return (u16)((u + 0x7fffu + ((u >> 16) & 1u)) >> 16);   // RNE
}
__device__ __forceinline__ unsigned cvt_pk_bf16(float lo, float hi) {
    unsigned r;
    asm("v_cvt_pk_bf16_f32 %0, %1, %2" : "=v"(r) : "v"(lo), "v"(hi));
    return r;
}
__device__ __forceinline__ float bf2f_lo(unsigned u) {
    union { unsigned u; float f; } v; v.u = u << 16; return v.f;
}
__device__ __forceinline__ float bf2f_hi(unsigned u) {
    union { unsigned u; float f; } v; v.u = u & 0xFFFF0000u; return v.f;
}
__device__ __forceinline__ float elu1(float x) {
    return x > 0.0f ? x : (__expf(x) - 1.0f);
}
__device__ __forceinline__ unsigned addelu_pk(unsigned a, unsigned b) {
    float s0 = elu1(bf2f_lo(a) + bf2f_lo(b));
    float s1 = elu1(bf2f_hi(a) + bf2f_hi(b));
    return cvt_pk_bf16(s0, s1);
}
// raw barrier: waits LDS ops only; global loads stay in flight (T4)
__device__ __forceinline__ void barrier_lds_only() {
    asm volatile("s_waitcnt lgkmcnt(0)" ::: "memory");
    __builtin_amdgcn_s_barrier();
    __builtin_amdgcn_sched_barrier(0);
}

__global__ void detect_idx64(const void* __restrict__ ei_raw, int* __restrict__ flag) {
    if (blockIdx.x == 0 && threadIdx.x == 0) {
        const unsigned long long* p = (const unsigned long long*)ei_raw;
        int is64 = 1;
        for (int i = 0; i < 64; ++i)
            if (p[i] >= (1ULL << 32)) { is64 = 0; break; }
        *flag = is64;
    }
}

// WAB[512][160] (row-major, for node_gemm) +
// W2f: fragment order [jb 16][kk 8][lane 64][8]: W2[jb*16+(l&15)][kk*32+((l>>4)<<3)+c]
// W3f: fragment order [ob  8][kk 8][lane 64][8]: W3[ob*16+(l&15)][kk*32+((l>>4)<<3)+c]
__global__ void prep_weights(const float* __restrict__ W0, const float* __restrict__ W2,
                             const float* __restrict__ W3, u16* __restrict__ WAB,
                             u16* __restrict__ W2f, u16* __restrict__ W3f) {
    int i = blockIdx.x * blockDim.x + threadIdx.x;
    const int nwab = 512 * 160, nw2 = 256 * 256, nw3 = 128 * 256;
    if (i < nwab) {
        int j = i / 160, k = i - j * 160;
        float v = 0.f;
        if (j < 256) {                       // A-weights (src role)
            if (k < 128) v = W0[j * IN_CH_C + 3 + k];
            else if (k < 131) v = -W0[j * IN_CH_C + (k - 128)];
        } else {                             // B-weights (dst role)
            int j2 = j - 256;
            if (k < 128) v = W0[j2 * IN_CH_C + 131 + k];
            else if (k < 131) v = W0[j2 * IN_CH_C + (k - 128)];
        }
        WAB[i] = f2bf(v);
    } else if (i < nwab + nw2) {
        int q = i - nwab;
        int c = q & 7, lIdx = (q >> 3) & 63, kk = (q >> 9) & 7, jb = q >> 12;
        int j = jb * 16 + (lIdx & 15);
        int k = kk * 32 + ((lIdx >> 4) << 3) + c;
        W2f[q] = f2bf(W2[j * 256 + k]);
    } else if (i < nwab + nw2 + nw3) {
        int q = i - nwab - nw2;
        int c = q & 7, lIdx = (q >> 3) & 63, kk = (q >> 9) & 7, ob = q >> 12;
        int o = ob * 16 + (lIdx & 15);
        int k = kk * 32 + ((lIdx >> 4) << 3) + c;
        W3f[q] = f2bf(W3[o * 256 + k]);
    }
}

// AB[n][0..255] = A[n] (+b0), AB[n][256..511] = B[n].  M=50000, N=512, K=160.
extern "C" __global__ void __launch_bounds__(512, 2)
node_gemm(const float* __restrict__ x, const float* __restrict__ pos,
          const u16* __restrict__ WAB, const float* __restrict__ b0,
          u16* __restrict__ AB) {
    __shared__ u16 tile[128 * 168];
    const int t = threadIdx.x;
    const int row0 = blockIdx.x * 128;
    for (int idx = t; idx < 128 * 80; idx += 512) {
        int m = idx / 80, wq = idx - m * 80;
        int k = wq * 2, n = row0 + m;
        float f0 = 0.f, f1 = 0.f;
        if (n < N_NODES_C) {
            f0 = (k < 128) ? x[(size_t)n * 128 + k] : (k < 131 ? pos[(size_t)n * 3 + k - 128] : 0.f);
            int k1 = k + 1;
            f1 = (k1 < 128) ? x[(size_t)n * 128 + k1] : (k1 < 131 ? pos[(size_t)n * 3 + k1 - 128] : 0.f);
        }
        *(unsigned*)&tile[m * 168 + k] = (unsigned)f2bf(f0) | ((unsigned)f2bf(f1) << 16);
    }
    __syncthreads();
    const int w = t >> 6, l = t & 63, lr = l & 15, hi = l >> 4;
    for (int mc = 0; mc < 2; ++mc) {
        f32x4 acc[4][4];
#pragma unroll
        for (int ji = 0; ji < 4; ++ji)
#pragma unroll
            for (int mi = 0; mi < 4; ++mi)
                acc[ji][mi] = (f32x4){0.f, 0.f, 0.f, 0.f};
#pragma unroll
        for (int kk = 0; kk < 5; ++kk) {
            bf16x8 af[4], bfr[4];
#pragma unroll
            for (int ji = 0; ji < 4; ++ji)
                af[ji] = *(const bf16x8*)&WAB[(size_t)(w * 64 + ji * 16 + lr) * 160 + kk * 32 + hi * 8];
#pragma unroll
            for (int mi = 0; mi < 4; ++mi)
                bfr[mi] = *(const bf16x8*)&tile[(mc * 64 + mi * 16 + lr) * 168 + kk * 32 + hi * 8];
#pragma unroll
            for (int ji = 0; ji < 4; ++ji)
#pragma unroll
                for (int mi = 0; mi < 4; ++mi)
                    acc[ji][mi] = __builtin_amdgcn_mfma_f32_16x16x32_bf16(af[ji], bfr[mi], acc[ji][mi], 0, 0, 0);
        }
#pragma unroll
        for (int ji = 0; ji < 4; ++ji) {
            int j0 = w * 64 + ji * 16 + hi * 4;
            float4 bb = make_float4(0.f, 0.f, 0.f, 0.f);
            if (j0 < 256) bb = *(const float4*)&b0[j0];
#pragma unroll
            for (int mi = 0; mi < 4; ++mi) {
                int nn = row0 + mc * 64 + mi * 16 + lr;
                if (nn < N_NODES_C) {
                    f32x4 v = acc[ji][mi];
                    uint2 pr;
                    pr.x = cvt_pk_bf16(v[0] + bb.x, v[1] + bb.y);
                    pr.y = cvt_pk_bf16(v[2] + bb.z, v[3] + bb.w);
                    *(uint2*)&AB[(size_t)nn * 512 + j0] = pr;
                }
            }
        }
    }
}

// Edge kernel round 7: persistent, VGPR-prefetched gather, raw barriers.
extern "C" __global__ void __launch_bounds__(512, 4)
edge_mlp_v7(const u16* __restrict__ AB, const void* __restrict__ ei_raw,
            const int* __restrict__ idx64_flag,
            const u16* __restrict__ W2f, const float* __restrict__ b2,
            const u16* __restrict__ W3f, const float* __restrict__ b3,
            float* __restrict__ out) {
    __shared__ u16 h1[BM7 * HSTR7];          // 33.8 KB
    __shared__ u16 h2[BM7 * HSTR7];          // 33.8 KB

    const int t = threadIdx.x;
    const int w = t >> 6, l = t & 63, lr = l & 15, hi = l >> 4;
    const int m = t >> 3, q = t & 7;         // phase0: edge m, 64B chunk q
    const int is64 = *idx64_flag;
    const long long* e64 = (const long long*)ei_raw;
    const int* e32 = (const int*)ei_raw;

    // hoisted biases
    float4 bb2[2];
#pragma unroll
    for (int ji = 0; ji < 2; ++ji)
        bb2[ji] = *(const float4*)&b2[w * 32 + ji * 16 + hi * 4];
    const float4 bb3 = *(const float4*)&b3[w * 16 + hi * 4];

    uint4 ga[4], gb[4];
#define GATHER(TL) do {                                                         \
        int eid = (TL) * BM7 + m;                                               \
        int sA, sB;                                                             \
        if (is64) { sA = (int)e64[eid]; sB = (int)e64[N_EDGES_C + eid]; }       \
        else      { sA = e32[eid];      sB = e32[N_EDGES_C + eid]; }            \
        const u16* ra = AB + (size_t)sA * 512 + q * 32;                         \
        const u16* rb = AB + (size_t)sB * 512 + 256 + q * 32;                   \
        _Pragma("unroll")                                                       \
        for (int i = 0; i < 4; ++i) { ga[i] = *(const uint4*)(ra + i * 8);      \
                                      gb[i] = *(const uint4*)(rb + i * 8); }    \
    } while (0)

    const int tile0 = blockIdx.x;
    GATHER(tile0);                            // prologue

    for (int tk = tile0; tk < NT7; tk += GRID7) {
        // ---- phase 0: consume prefetched regs -> h1; then issue next gather ----
#pragma unroll
        for (int i = 0; i < 4; ++i) {
            uint4 r;
            r.x = addelu_pk(ga[i].x, gb[i].x);
            r.y = addelu_pk(ga[i].y, gb[i].y);
            r.z = addelu_pk(ga[i].z, gb[i].z);
            r.w = addelu_pk(ga[i].w, gb[i].w);
            *(uint4*)&h1[m * HSTR7 + q * 32 + i * 8] = r;
        }
        if (tk + GRID7 < NT7) GATHER(tk + GRID7);   // flies across raw barriers

        barrier_lds_only();                           // B1: h1 ready (vmcnt kept)

        // ---- layer 1 (swapped): D[j][m] = W2[j][:] . h1[m][:] + b2 ----
        // wave w owns j-block w*32 (ji 0..1) x all m (mi 0..3) -> dup-free
        f32x4 acc[2][4];
#pragma unroll
        for (int ji = 0; ji < 2; ++ji)
#pragma unroll
            for (int mi = 0; mi < 4; ++mi)
                acc[ji][mi] = (f32x4){bb2[ji].x, bb2[ji].y, bb2[ji].z, bb2[ji].w};
        __builtin_amdgcn_s_setprio(1);
#pragma unroll
        for (int kk = 0; kk < 8; ++kk) {
            bf16x8 af[2], bfr[4];
#pragma unroll
            for (int ji = 0; ji < 2; ++ji)
                af[ji] = *(const bf16x8*)&W2f[(size_t)(((w * 2 + ji) * 8 + kk) * 64 + l) * 8];
#pragma unroll
            for (int mi = 0; mi < 4; ++mi)
                bfr[mi] = *(const bf16x8*)&h1[(mi * 16 + lr) * HSTR7 + kk * 32 + hi * 8];
#pragma unroll
            for (int ji = 0; ji < 2; ++ji)
#pragma unroll
                for (int mi = 0; mi < 4; ++mi)
                    acc[ji][mi] = __builtin_amdgcn_mfma_f32_16x16x32_bf16(af[ji], bfr[mi], acc[ji][mi], 0, 0, 0);
        }
        __builtin_amdgcn_s_setprio(0);

        // epilogue: h2[m][j] = elu(D[j][m]); lane holds 4 consecutive j
#pragma unroll
        for (int ji = 0; ji < 2; ++ji) {
            int j0 = w * 32 + ji * 16 + hi * 4;
#pragma unroll
            for (int mi = 0; mi < 4; ++mi) {
                int mm = mi * 16 + lr;
                f32x4 v = acc[ji][mi];
                uint2 pr;
                pr.x = cvt_pk_bf16(elu1(v[0]), elu1(v[1]));
                pr.y = cvt_pk_bf16(elu1(v[2]), elu1(v[3]));
                *(uint2*)&h2[mm * HSTR7 + j0] = pr;
            }
        }
        barrier_lds_only();                           // B2: h2 ready (vmcnt kept)

        // ---- layer 2 (swapped): D[o][m] = W3[o][:] . h2[m][:] + b3 ----
        // wave w owns o-block w*16 x all m -> dup-free
        f32x4 acc2[4];                                // [mi]; reg r -> o = w*16+hi*4+r
#pragma unroll
        for (int mi = 0; mi < 4; ++mi)
            acc2[mi] = (f32x4){bb3.x, bb3.y, bb3.z, bb3.w};
        __builtin_amdgcn_s_setprio(1);
#pragma unroll
        for (int kk = 0; kk < 8; ++kk) {
            bf16x8 af3, bh[4];
            af3 = *(const bf16x8*)&W3f[(size_t)((w * 8 + kk) * 64 + l) * 8];
#pragma unroll
            for (int mi = 0; mi < 4; ++mi)
                bh[mi] = *(const bf16x8*)&h2[(mi * 16 + lr) * HSTR7 + kk * 32 + hi * 8];
#pragma unroll
            for (int mi = 0; mi < 4; ++mi)
                acc2[mi] = __builtin_amdgcn_mfma_f32_16x16x32_bf16(af3, bh[mi], acc2[mi], 0, 0, 0);
        }
        __builtin_amdgcn_s_setprio(0);

        // store: lane (lr,hi) holds out[m = mi*16+lr][o = w*16+hi*4 .. +3]
#pragma unroll
        for (int mi = 0; mi < 4; ++mi) {
            f32x4 v = acc2[mi];
            float4 o4;
            o4.x = v[0]; o4.y = v[1]; o4.z = v[2]; o4.w = v[3];
            *(float4*)&out[(size_t)(tk * BM7 + mi * 16 + lr) * 128 + w * 16 + hi * 4] = o4;
        }
        // loop: phase0(t+1) h1-writes safe (B2 passed => all layer1 h1-reads done);
        //       layer2(t) h2-reads safe vs epilogue(t+1) writes (B1(t+1) between).
    }
#undef GATHER
}

// ---------------- round-1 f32 fallback (ws too small) ----------------
#define BM 64
#define PAD 65
__global__ void transpose_f32(const float* __restrict__ src, float* __restrict__ dst, int R, int C) {
    int i = blockIdx.x * blockDim.x + threadIdx.x;
    if (i < R * C) { int c = i / R; int r = i - c * R; dst[i] = src[r * C + c]; }
}
__device__ __forceinline__ void layer256(const float* __restrict__ wt, const float* __restrict__ b,
                                         const float* in_lds, float* out_lds, int K, int t) {
    const int jg = t & 63, mc = t >> 6;
    const float* wp = wt + jg * 4;
    const float4 bv = *(const float4*)&b[jg * 4];
    float acc[8][4];
#pragma unroll
    for (int i = 0; i < 8; ++i) { acc[i][0] = bv.x; acc[i][1] = bv.y; acc[i][2] = bv.z; acc[i][3] = bv.w; }
    const float* hbase = in_lds + mc * 8;
    float4 wv = *(const float4*)wp;
    for (int k = 0; k < K; ++k) {
        float4 wn = wv;
        if (k + 1 < K) wn = *(const float4*)(wp + (size_t)(k + 1) * HID_C);
        float h[8];
#pragma unroll
        for (int i = 0; i < 8; ++i) h[i] = hbase[k * PAD + i];
#pragma unroll
        for (int i = 0; i < 8; ++i) {
            acc[i][0] += h[i] * wv.x; acc[i][1] += h[i] * wv.y;
            acc[i][2] += h[i] * wv.z; acc[i][3] += h[i] * wv.w;
        }
        wv = wn;
    }
#pragma unroll
    for (int i4 = 0; i4 < 4; ++i4)
#pragma unroll
        for (int i = 0; i < 8; ++i) {
            float v = acc[i][i4];
            v = v > 0.0f ? v : expm1f(v);
            out_lds[(jg * 4 + i4) * PAD + mc * 8 + i] = v;
        }
}
extern "C" __global__ void __launch_bounds__(512, 2)
edge_mlp_f32(const float* __restrict__ x, const void* __restrict__ ei_raw,
             const float* __restrict__ pos, const int* __restrict__ idx64_flag,
             const float* __restrict__ wt0, const float* __restrict__ b0,
             const float* __restrict__ wt2, const float* __restrict__ b2,
             const float* __restrict__ wt3, const float* __restrict__ b3,
             float* __restrict__ out) {
    __shared__ float buf1[IN_CH_C * PAD];
    __shared__ float buf2[HID_C * PAD];
    __shared__ int s_src[BM], s_dst[BM];
    const int t = threadIdx.x;
    const int e0 = blockIdx.x * BM;
    if (t < BM) {
        int s, d;
        if (*idx64_flag) {
            const long long* e = (const long long*)ei_raw;
            s = (int)e[e0 + t]; d = (int)e[N_EDGES_C + e0 + t];
        } else {
            const int* e = (const int*)ei_raw;
            s = e[e0 + t]; d = e[N_EDGES_C + e0 + t];
        }
        s_src[t] = s; s_dst[t] = d;
    }
    __syncthreads();
    if (t < BM) {
        const int s = s_src[t], d = s_dst[t];
#pragma unroll
        for (int i = 0; i < 3; ++i)
            buf1[i * PAD + t] = pos[d * 3 + i] - pos[s * 3 + i];
    }
    {
        const int l = t & 31, grp = t >> 5;
#pragma unroll
        for (int r = 0; r < 4; ++r) {
            const int m = grp + r * 16;
            const int s = s_src[m], d = s_dst[m];
            const float4 xi = *(const float4*)&x[(size_t)s * D_FEAT_C + l * 4];
            const float4 xj = *(const float4*)&x[(size_t)d * D_FEAT_C + l * 4];
            buf1[(3 + l * 4 + 0) * PAD + m] = xi.x; buf1[(3 + l * 4 + 1) * PAD + m] = xi.y;
            buf1[(3 + l * 4 + 2) * PAD + m] = xi.z; buf1[(3 + l * 4 + 3) * PAD + m] = xi.w;
            buf1[(131 + l * 4 + 0) * PAD + m] = xj.x; buf1[(131 + l * 4 + 1) * PAD + m] = xj.y;
            buf1[(131 + l * 4 + 2) * PAD + m] = xj.z; buf1[(131 + l * 4 + 3) * PAD + m] = xj.w;
        }
    }
    __syncthreads();
    layer256(wt0, b0, buf1, buf2, IN_CH_C, t);
    __syncthreads();
    layer256(wt2, b2, buf2, buf1, HID_C, t);
    __syncthreads();
    {
        const int jg = t & 31, mc = t >> 5;
        const float* wp = wt3 + jg * 4;
        const float4 bv = *(const float4*)&b3[jg * 4];
        float acc[4][4];
#pragma unroll
        for (int i = 0; i < 4; ++i) { acc[i][0] = bv.x; acc[i][1] = bv.y; acc[i][2] = bv.z; acc[i][3] = bv.w; }
        const float* hbase = buf1 + mc * 4;
        float4 wv = *(const float4*)wp;
        for (int k = 0; k < HID_C; ++k) {
            float4 wn = wv;
            if (k + 1 < HID_C) wn = *(const float4*)(wp + (size_t)(k + 1) * OUT_CH_C);
            float h[4];
#pragma unroll
            for (int i = 0; i < 4; ++i) h[i] = hbase[k * PAD + i];
#pragma unroll
            for (int i = 0; i < 4; ++i) {
                acc[i][0] += h[i] * wv.x; acc[i][1] += h[i] * wv.y;
                acc[i][2] += h[i] * wv.z; acc[i][3] += h[i] * wv.w;
            }
            wv = wn;
        }
#pragma unroll
        for (int i = 0; i < 4; ++i) {
            float4 o;
            o.x = acc[i][0]; o.y = acc[i][1]; o.z = acc[i][2]; o.w = acc[i][3];
            *(float4*)&out[(size_t)(e0 + mc * 4 + i) * OUT_CH_C + jg * 4] = o;
        }
    }
}

extern "C" void kernel_launch(void* const* d_in, const int* in_sizes, int n_in,
                              void* d_out, int out_size, void* d_ws, size_t ws_size,
                              hipStream_t stream) {
    const float* x   = (const float*)d_in[0];
    const void*  ei  = d_in[1];
    const float* pos = (const float*)d_in[2];
    const float* W0  = (const float*)d_in[3];
    const float* b0  = (const float*)d_in[4];
    const float* W2  = (const float*)d_in[5];
    const float* b2  = (const float*)d_in[6];
    const float* W3  = (const float*)d_in[7];
    const float* b3  = (const float*)d_in[8];
    float* out = (float*)d_out;

    const size_t need = (size_t)N_NODES_C * 512 * 2 + (size_t)512 * 160 * 2
                      + (size_t)256 * 256 * 2 + (size_t)128 * 256 * 2 + 16;
    if (ws_size >= need) {
        u16* AB  = (u16*)d_ws;                         // [50000][512]
        u16* WAB = AB + (size_t)N_NODES_C * 512;       // [512][160]
        u16* W2f = WAB + 512 * 160;                    // fragment-order [16][8][64][8]
        u16* W3f = W2f + 256 * 256;                    // fragment-order [8][8][64][8]
        int* flag = (int*)(W3f + 128 * 256);

        detect_idx64<<<1, 64, 0, stream>>>(ei, flag);
        prep_weights<<<704, 256, 0, stream>>>(W0, W2, W3, WAB, W2f, W3f);
        node_gemm<<<391, 512, 0, stream>>>(x, pos, WAB, b0, AB);
        edge_mlp_v7<<<GRID7, 512, 0, stream>>>(AB, ei, flag, W2f, b2, W3f, b3, out);
    } else {
        float* wt0 = (float*)d_ws;
        float* wt2 = wt0 + IN_CH_C * HID_C;
        float* wt3 = wt2 + HID_C * HID_C;
        int*   flag = (int*)(wt3 + HID_C * OUT_CH_C);

        detect_idx64<<<1, 64, 0, stream>>>(ei, flag);
        int n0 = HID_C * IN_CH_C;
        transpose_f32<<<(n0 + 255) / 256, 256, 0, stream>>>(W0, wt0, HID_C, IN_CH_C);
        int n2 = HID_C * HID_C;
        transpose_f32<<<(n2 + 255) / 256, 256, 0, stream>>>(W2, wt2, HID_C, HID_C);
        int n3 = OUT_CH_C * HID_C;
        transpose_f32<<<(n3 + 255) / 256, 256, 0, stream>>>(W3, wt3, OUT_CH_C, HID_C);
        edge_mlp_f32<<<N_EDGES_C / BM, 512, 0, stream>>>(
            x, ei, pos, flag, wt0, b0, wt2, b2, wt3, b3, out);
    }
}

// Round 8
// 369.737 us; speedup vs baseline: 1.3825x; 1.3825x over previous
//
#include <hip/hip_runtime.h>
#include <cstddef>
#include <cstdint>

// EdgeNet bf16-MFMA pipeline, round 8:
//   AB[n] precomputed per node (A = x@W0i^T - pos@W0e^T + b0 | B = x@W0j^T + pos@W0e^T)
//   Edge kernel: NON-persistent 12500 blocks x 512 thr (8 waves), BM=64.
//   Separate h1/h2 LDS buffers -> 2 barriers. XOR-swizzled LDS (T2) kills the
//   4-way bank aliasing (r6: 2.56e7 conflicts). Dup-free per-wave weight tiles
//   (j-32 L1, o-16 L2). 2 blocks/CU -> 16 waves/CU.

#define N_NODES_C 50000
#define N_EDGES_C 800000
#define D_FEAT_C  128
#define IN_CH_C   259
#define HID_C     256
#define OUT_CH_C  128

#define BM8    64
#define HSTR8  272                   // u16 row stride (544B, 16B-aligned)
// XOR swizzle: col in u16 units, 8-u16 (16B) chunk granularity
#define SW(row, c) ((c) ^ (((row) & 7) << 3))

typedef unsigned short u16;
typedef short bf16x8 __attribute__((ext_vector_type(8)));
typedef float f32x4 __attribute__((ext_vector_type(4)));

__device__ __forceinline__ u16 f2bf(float f) {
    union { float f; unsigned u; } v; v.f = f;
    unsigned u = v.u;
    return (u16)((u + 0x7fffu + ((u >> 16) & 1u)) >> 16);   // RNE
}
__device__ __forceinline__ unsigned cvt_pk_bf16(float lo, float hi) {
    unsigned r;
    asm("v_cvt_pk_bf16_f32 %0, %1, %2" : "=v"(r) : "v"(lo), "v"(hi));
    return r;
}
__device__ __forceinline__ float bf2f_lo(unsigned u) {
    union { unsigned u; float f; } v; v.u = u << 16; return v.f;
}
__device__ __forceinline__ float bf2f_hi(unsigned u) {
    union { unsigned u; float f; } v; v.u = u & 0xFFFF0000u; return v.f;
}
__device__ __forceinline__ float elu1(float x) {
    return x > 0.0f ? x : (__expf(x) - 1.0f);
}
__device__ __forceinline__ unsigned addelu_pk(unsigned a, unsigned b) {
    float s0 = elu1(bf2f_lo(a) + bf2f_lo(b));
    float s1 = elu1(bf2f_hi(a) + bf2f_hi(b));
    return cvt_pk_bf16(s0, s1);
}

__global__ void detect_idx64(const void* __restrict__ ei_raw, int* __restrict__ flag) {
    if (blockIdx.x == 0 && threadIdx.x == 0) {
        const unsigned long long* p = (const unsigned long long*)ei_raw;
        int is64 = 1;
        for (int i = 0; i < 64; ++i)
            if (p[i] >= (1ULL << 32)) { is64 = 0; break; }
        *flag = is64;
    }
}

// WAB[512][160] (row-major, for node_gemm) +
// W2f: fragment order [jb 16][kk 8][lane 64][8]: W2[jb*16+(l&15)][kk*32+((l>>4)<<3)+c]
// W3f: fragment order [ob  8][kk 8][lane 64][8]: W3[ob*16+(l&15)][kk*32+((l>>4)<<3)+c]
__global__ void prep_weights(const float* __restrict__ W0, const float* __restrict__ W2,
                             const float* __restrict__ W3, u16* __restrict__ WAB,
                             u16* __restrict__ W2f, u16* __restrict__ W3f) {
    int i = blockIdx.x * blockDim.x + threadIdx.x;
    const int nwab = 512 * 160, nw2 = 256 * 256, nw3 = 128 * 256;
    if (i < nwab) {
        int j = i / 160, k = i - j * 160;
        float v = 0.f;
        if (j < 256) {                       // A-weights (src role)
            if (k < 128) v = W0[j * IN_CH_C + 3 + k];
            else if (k < 131) v = -W0[j * IN_CH_C + (k - 128)];
        } else {                             // B-weights (dst role)
            int j2 = j - 256;
            if (k < 128) v = W0[j2 * IN_CH_C + 131 + k];
            else if (k < 131) v = W0[j2 * IN_CH_C + (k - 128)];
        }
        WAB[i] = f2bf(v);
    } else if (i < nwab + nw2) {
        int q = i - nwab;
        int c = q & 7, lIdx = (q >> 3) & 63, kk = (q >> 9) & 7, jb = q >> 12;
        int j = jb * 16 + (lIdx & 15);
        int k = kk * 32 + ((lIdx >> 4) << 3) + c;
        W2f[q] = f2bf(W2[j * 256 + k]);
    } else if (i < nwab + nw2 + nw3) {
        int q = i - nwab - nw2;
        int c = q & 7, lIdx = (q >> 3) & 63, kk = (q >> 9) & 7, ob = q >> 12;
        int o = ob * 16 + (lIdx & 15);
        int k = kk * 32 + ((lIdx >> 4) << 3) + c;
        W3f[q] = f2bf(W3[o * 256 + k]);
    }
}

// AB[n][0..255] = A[n] (+b0), AB[n][256..511] = B[n].  M=50000, N=512, K=160.
extern "C" __global__ void __launch_bounds__(512, 2)
node_gemm(const float* __restrict__ x, const float* __restrict__ pos,
          const u16* __restrict__ WAB, const float* __restrict__ b0,
          u16* __restrict__ AB) {
    __shared__ u16 tile[128 * 168];
    const int t = threadIdx.x;
    const int row0 = blockIdx.x * 128;
    for (int idx = t; idx < 128 * 80; idx += 512) {
        int m = idx / 80, wq = idx - m * 80;
        int k = wq * 2, n = row0 + m;
        float f0 = 0.f, f1 = 0.f;
        if (n < N_NODES_C) {
            f0 = (k < 128) ? x[(size_t)n * 128 + k] : (k < 131 ? pos[(size_t)n * 3 + k - 128] : 0.f);
            int k1 = k + 1;
            f1 = (k1 < 128) ? x[(size_t)n * 128 + k1] : (k1 < 131 ? pos[(size_t)n * 3 + k1 - 128] : 0.f);
        }
        *(unsigned*)&tile[m * 168 + k] = (unsigned)f2bf(f0) | ((unsigned)f2bf(f1) << 16);
    }
    __syncthreads();
    const int w = t >> 6, l = t & 63, lr = l & 15, hi = l >> 4;
    for (int mc = 0; mc < 2; ++mc) {
        f32x4 acc[4][4];
#pragma unroll
        for (int ji = 0; ji < 4; ++ji)
#pragma unroll
            for (int mi = 0; mi < 4; ++mi)
                acc[ji][mi] = (f32x4){0.f, 0.f, 0.f, 0.f};
#pragma unroll
        for (int kk = 0; kk < 5; ++kk) {
            bf16x8 af[4], bfr[4];
#pragma unroll
            for (int ji = 0; ji < 4; ++ji)
                af[ji] = *(const bf16x8*)&WAB[(size_t)(w * 64 + ji * 16 + lr) * 160 + kk * 32 + hi * 8];
#pragma unroll
            for (int mi = 0; mi < 4; ++mi)
                bfr[mi] = *(const bf16x8*)&tile[(mc * 64 + mi * 16 + lr) * 168 + kk * 32 + hi * 8];
#pragma unroll
            for (int ji = 0; ji < 4; ++ji)
#pragma unroll
                for (int mi = 0; mi < 4; ++mi)
                    acc[ji][mi] = __builtin_amdgcn_mfma_f32_16x16x32_bf16(af[ji], bfr[mi], acc[ji][mi], 0, 0, 0);
        }
#pragma unroll
        for (int ji = 0; ji < 4; ++ji) {
            int j0 = w * 64 + ji * 16 + hi * 4;
            float4 bb = make_float4(0.f, 0.f, 0.f, 0.f);
            if (j0 < 256) bb = *(const float4*)&b0[j0];
#pragma unroll
            for (int mi = 0; mi < 4; ++mi) {
                int nn = row0 + mc * 64 + mi * 16 + lr;
                if (nn < N_NODES_C) {
                    f32x4 v = acc[ji][mi];
                    uint2 pr;
                    pr.x = cvt_pk_bf16(v[0] + bb.x, v[1] + bb.y);
                    pr.y = cvt_pk_bf16(v[2] + bb.z, v[3] + bb.w);
                    *(uint2*)&AB[(size_t)nn * 512 + j0] = pr;
                }
            }
        }
    }
}

// Edge kernel round 8: 64 edges/block, 8 waves, swizzled LDS, 2 barriers.
extern "C" __global__ void __launch_bounds__(512, 4)
edge_mlp_v8(const u16* __restrict__ AB, const void* __restrict__ ei_raw,
            const int* __restrict__ idx64_flag,
            const u16* __restrict__ W2f, const float* __restrict__ b2,
            const u16* __restrict__ W3f, const float* __restrict__ b3,
            float* __restrict__ out) {
    __shared__ u16 h1[BM8 * HSTR8];          // 34.8 KB
    __shared__ u16 h2[BM8 * HSTR8];          // 34.8 KB

    const int t = threadIdx.x;
    const int e0 = blockIdx.x * BM8;
    const int w = t >> 6, l = t & 63, lr = l & 15, hi = l >> 4;

    // ---- phase 0: gather + h1 = elu(A[src] + B[dst]) ----
    // thread t: edge m = t>>3, 64B chunk q = t&7 (32 u16 of A + 32 of B)
    {
        const int m = t >> 3, q = t & 7;
        const int eid = e0 + m;
        int sA, sB;
        if (*idx64_flag) {
            const long long* e = (const long long*)ei_raw;
            sA = (int)e[eid]; sB = (int)e[N_EDGES_C + eid];
        } else {
            const int* e = (const int*)ei_raw;
            sA = e[eid]; sB = e[N_EDGES_C + eid];
        }
        const u16* ra = AB + (size_t)sA * 512 + q * 32;
        const u16* rb = AB + (size_t)sB * 512 + 256 + q * 32;
        uint4 a[4], b[4];
#pragma unroll
        for (int i = 0; i < 4; ++i) a[i] = *(const uint4*)(ra + i * 8);
#pragma unroll
        for (int i = 0; i < 4; ++i) b[i] = *(const uint4*)(rb + i * 8);
#pragma unroll
        for (int i = 0; i < 4; ++i) {
            uint4 r;
            r.x = addelu_pk(a[i].x, b[i].x);
            r.y = addelu_pk(a[i].y, b[i].y);
            r.z = addelu_pk(a[i].z, b[i].z);
            r.w = addelu_pk(a[i].w, b[i].w);
            *(uint4*)&h1[m * HSTR8 + SW(m, q * 32 + i * 8)] = r;
        }
    }
    __syncthreads();                                      // B1: h1 ready

    // ---- layer 1 (swapped): D[j][m] = W2[j][:] . h1[m][:] + b2 ----
    // wave w owns j-block w*32 (ji 0..1) x all m (mi 0..3) -> dup-free
    f32x4 acc[2][4];
#pragma unroll
    for (int ji = 0; ji < 2; ++ji) {
        const float4 bb = *(const float4*)&b2[w * 32 + ji * 16 + hi * 4];
#pragma unroll
        for (int mi = 0; mi < 4; ++mi)
            acc[ji][mi] = (f32x4){bb.x, bb.y, bb.z, bb.w};
    }
    __builtin_amdgcn_s_setprio(1);
#pragma unroll
    for (int kk = 0; kk < 8; ++kk) {
        bf16x8 af[2], bfr[4];
#pragma unroll
        for (int ji = 0; ji < 2; ++ji)                     // coalesced 1KB fragment loads
            af[ji] = *(const bf16x8*)&W2f[(size_t)(((w * 2 + ji) * 8 + kk) * 64 + l) * 8];
#pragma unroll
        for (int mi = 0; mi < 4; ++mi) {
            int row = mi * 16 + lr;
            bfr[mi] = *(const bf16x8*)&h1[row * HSTR8 + SW(row, kk * 32 + hi * 8)];
        }
#pragma unroll
        for (int ji = 0; ji < 2; ++ji)
#pragma unroll
            for (int mi = 0; mi < 4; ++mi)
                acc[ji][mi] = __builtin_amdgcn_mfma_f32_16x16x32_bf16(af[ji], bfr[mi], acc[ji][mi], 0, 0, 0);
    }
    __builtin_amdgcn_s_setprio(0);

    // epilogue: h2[m][j] = elu(D[j][m]); separate buffer -> no barrier needed here
#pragma unroll
    for (int ji = 0; ji < 2; ++ji) {
        int j0 = w * 32 + ji * 16 + hi * 4;
#pragma unroll
        for (int mi = 0; mi < 4; ++mi) {
            int mm = mi * 16 + lr;
            f32x4 v = acc[ji][mi];
            uint2 pr;
            pr.x = cvt_pk_bf16(elu1(v[0]), elu1(v[1]));
            pr.y = cvt_pk_bf16(elu1(v[2]), elu1(v[3]));
            *(uint2*)&h2[mm * HSTR8 + SW(mm, j0)] = pr;    // 4-aligned col: XOR flips bits>=3 only
        }
    }
    __syncthreads();                                      // B2: h2 ready

    // ---- layer 2 (swapped): D[o][m] = W3[o][:] . h2[m][:] + b3 ----
    // wave w owns o-block w*16 x all m -> dup-free
    f32x4 acc2[4];                                        // [mi]; reg r -> o = w*16+hi*4+r
    {
        const float4 bv = *(const float4*)&b3[w * 16 + hi * 4];
#pragma unroll
        for (int mi = 0; mi < 4; ++mi)
            acc2[mi] = (f32x4){bv.x, bv.y, bv.z, bv.w};
    }
    __builtin_amdgcn_s_setprio(1);
#pragma unroll
    for (int kk = 0; kk < 8; ++kk) {
        bf16x8 af3, bh[4];
        af3 = *(const bf16x8*)&W3f[(size_t)((w * 8 + kk) * 64 + l) * 8];
#pragma unroll
        for (int mi = 0; mi < 4; ++mi) {
            int row = mi * 16 + lr;
            bh[mi] = *(const bf16x8*)&h2[row * HSTR8 + SW(row, kk * 32 + hi * 8)];
        }
#pragma unroll
        for (int mi = 0; mi < 4; ++mi)
            acc2[mi] = __builtin_amdgcn_mfma_f32_16x16x32_bf16(af3, bh[mi], acc2[mi], 0, 0, 0);
    }
    __builtin_amdgcn_s_setprio(0);

    // store: lane (lr,hi) holds out[m = mi*16+lr][o = w*16+hi*4 .. +3]
#pragma unroll
    for (int mi = 0; mi < 4; ++mi) {
        f32x4 v = acc2[mi];
        float4 o4;
        o4.x = v[0]; o4.y = v[1]; o4.z = v[2]; o4.w = v[3];
        *(float4*)&out[(size_t)(e0 + mi * 16 + lr) * 128 + w * 16 + hi * 4] = o4;
    }
}

// ---------------- round-1 f32 fallback (ws too small) ----------------
#define BM 64
#define PAD 65
__global__ void transpose_f32(const float* __restrict__ src, float* __restrict__ dst, int R, int C) {
    int i = blockIdx.x * blockDim.x + threadIdx.x;
    if (i < R * C) { int c = i / R; int r = i - c * R; dst[i] = src[r * C + c]; }
}
__device__ __forceinline__ void layer256(const float* __restrict__ wt, const float* __restrict__ b,
                                         const float* in_lds, float* out_lds, int K, int t) {
    const int jg = t & 63, mc = t >> 6;
    const float* wp = wt + jg * 4;
    const float4 bv = *(const float4*)&b[jg * 4];
    float acc[8][4];
#pragma unroll
    for (int i = 0; i < 8; ++i) { acc[i][0] = bv.x; acc[i][1] = bv.y; acc[i][2] = bv.z; acc[i][3] = bv.w; }
    const float* hbase = in_lds + mc * 8;
    float4 wv = *(const float4*)wp;
    for (int k = 0; k < K; ++k) {
        float4 wn = wv;
        if (k + 1 < K) wn = *(const float4*)(wp + (size_t)(k + 1) * HID_C);
        float h[8];
#pragma unroll
        for (int i = 0; i < 8; ++i) h[i] = hbase[k * PAD + i];
#pragma unroll
        for (int i = 0; i < 8; ++i) {
            acc[i][0] += h[i] * wv.x; acc[i][1] += h[i] * wv.y;
            acc[i][2] += h[i] * wv.z; acc[i][3] += h[i] * wv.w;
        }
        wv = wn;
    }
#pragma unroll
    for (int i4 = 0; i4 < 4; ++i4)
#pragma unroll
        for (int i = 0; i < 8; ++i) {
            float v = acc[i][i4];
            v = v > 0.0f ? v : expm1f(v);
            out_lds[(jg * 4 + i4) * PAD + mc * 8 + i] = v;
        }
}
extern "C" __global__ void __launch_bounds__(512, 2)
edge_mlp_f32(const float* __restrict__ x, const void* __restrict__ ei_raw,
             const float* __restrict__ pos, const int* __restrict__ idx64_flag,
             const float* __restrict__ wt0, const float* __restrict__ b0,
             const float* __restrict__ wt2, const float* __restrict__ b2,
             const float* __restrict__ wt3, const float* __restrict__ b3,
             float* __restrict__ out) {
    __shared__ float buf1[IN_CH_C * PAD];
    __shared__ float buf2[HID_C * PAD];
    __shared__ int s_src[BM], s_dst[BM];
    const int t = threadIdx.x;
    const int e0 = blockIdx.x * BM;
    if (t < BM) {
        int s, d;
        if (*idx64_flag) {
            const long long* e = (const long long*)ei_raw;
            s = (int)e[e0 + t]; d = (int)e[N_EDGES_C + e0 + t];
        } else {
            const int* e = (const int*)ei_raw;
            s = e[e0 + t]; d = e[N_EDGES_C + e0 + t];
        }
        s_src[t] = s; s_dst[t] = d;
    }
    __syncthreads();
    if (t < BM) {
        const int s = s_src[t], d = s_dst[t];
#pragma unroll
        for (int i = 0; i < 3; ++i)
            buf1[i * PAD + t] = pos[d * 3 + i] - pos[s * 3 + i];
    }
    {
        const int l = t & 31, grp = t >> 5;
#pragma unroll
        for (int r = 0; r < 4; ++r) {
            const int m = grp + r * 16;
            const int s = s_src[m], d = s_dst[m];
            const float4 xi = *(const float4*)&x[(size_t)s * D_FEAT_C + l * 4];
            const float4 xj = *(const float4*)&x[(size_t)d * D_FEAT_C + l * 4];
            buf1[(3 + l * 4 + 0) * PAD + m] = xi.x; buf1[(3 + l * 4 + 1) * PAD + m] = xi.y;
            buf1[(3 + l * 4 + 2) * PAD + m] = xi.z; buf1[(3 + l * 4 + 3) * PAD + m] = xi.w;
            buf1[(131 + l * 4 + 0) * PAD + m] = xj.x; buf1[(131 + l * 4 + 1) * PAD + m] = xj.y;
            buf1[(131 + l * 4 + 2) * PAD + m] = xj.z; buf1[(131 + l * 4 + 3) * PAD + m] = xj.w;
        }
    }
    __syncthreads();
    layer256(wt0, b0, buf1, buf2, IN_CH_C, t);
    __syncthreads();
    layer256(wt2, b2, buf2, buf1, HID_C, t);
    __syncthreads();
    {
        const int jg = t & 31, mc = t >> 5;
        const float* wp = wt3 + jg * 4;
        const float4 bv = *(const float4*)&b3[jg * 4];
        float acc[4][4];
#pragma unroll
        for (int i = 0; i < 4; ++i) { acc[i][0] = bv.x; acc[i][1] = bv.y; acc[i][2] = bv.z; acc[i][3] = bv.w; }
        const float* hbase = buf1 + mc * 4;
        float4 wv = *(const float4*)wp;
        for (int k = 0; k < HID_C; ++k) {
            float4 wn = wv;
            if (k + 1 < HID_C) wn = *(const float4*)(wp + (size_t)(k + 1) * OUT_CH_C);
            float h[4];
#pragma unroll
            for (int i = 0; i < 4; ++i) h[i] = hbase[k * PAD + i];
#pragma unroll
            for (int i = 0; i < 4; ++i) {
                acc[i][0] += h[i] * wv.x; acc[i][1] += h[i] * wv.y;
                acc[i][2] += h[i] * wv.z; acc[i][3] += h[i] * wv.w;
            }
            wv = wn;
        }
#pragma unroll
        for (int i = 0; i < 4; ++i) {
            float4 o;
            o.x = acc[i][0]; o.y = acc[i][1]; o.z = acc[i][2]; o.w = acc[i][3];
            *(float4*)&out[(size_t)(e0 + mc * 4 + i) * OUT_CH_C + jg * 4] = o;
        }
    }
}

extern "C" void kernel_launch(void* const* d_in, const int* in_sizes, int n_in,
                              void* d_out, int out_size, void* d_ws, size_t ws_size,
                              hipStream_t stream) {
    const float* x   = (const float*)d_in[0];
    const void*  ei  = d_in[1];
    const float* pos = (const float*)d_in[2];
    const float* W0  = (const float*)d_in[3];
    const float* b0  = (const float*)d_in[4];
    const float* W2  = (const float*)d_in[5];
    const float* b2  = (const float*)d_in[6];
    const float* W3  = (const float*)d_in[7];
    const float* b3  = (const float*)d_in[8];
    float* out = (float*)d_out;

    const size_t need = (size_t)N_NODES_C * 512 * 2 + (size_t)512 * 160 * 2
                      + (size_t)256 * 256 * 2 + (size_t)128 * 256 * 2 + 16;
    if (ws_size >= need) {
        u16* AB  = (u16*)d_ws;                         // [50000][512]
        u16* WAB = AB + (size_t)N_NODES_C * 512;       // [512][160]
        u16* W2f = WAB + 512 * 160;                    // fragment-order [16][8][64][8]
        u16* W3f = W2f + 256 * 256;                    // fragment-order [8][8][64][8]
        int* flag = (int*)(W3f + 128 * 256);

        detect_idx64<<<1, 64, 0, stream>>>(ei, flag);
        prep_weights<<<704, 256, 0, stream>>>(W0, W2, W3, WAB, W2f, W3f);
        node_gemm<<<391, 512, 0, stream>>>(x, pos, WAB, b0, AB);
        edge_mlp_v8<<<N_EDGES_C / BM8, 512, 0, stream>>>(AB, ei, flag, W2f, b2, W3f, b3, out);
    } else {
        float* wt0 = (float*)d_ws;
        float* wt2 = wt0 + IN_CH_C * HID_C;
        float* wt3 = wt2 + HID_C * HID_C;
        int*   flag = (int*)(wt3 + HID_C * OUT_CH_C);

        detect_idx64<<<1, 64, 0, stream>>>(ei, flag);
        int n0 = HID_C * IN_CH_C;
        transpose_f32<<<(n0 + 255) / 256, 256, 0, stream>>>(W0, wt0, HID_C, IN_CH_C);
        int n2 = HID_C * HID_C;
        transpose_f32<<<(n2 + 255) / 256, 256, 0, stream>>>(W2, wt2, HID_C, HID_C);
        int n3 = OUT_CH_C * HID_C;
        transpose_f32<<<(n3 + 255) / 256, 256, 0, stream>>>(W3, wt3, OUT_CH_C, HID_C);
        edge_mlp_f32<<<N_EDGES_C / BM, 512, 0, stream>>>(
            x, ei, pos, flag, wt0, b0, wt2, b2, wt3, b3, out);
    }
}

// Round 10
// 346.399 us; speedup vs baseline: 1.4756x; 1.0674x over previous
//
#include <hip/hip_runtime.h>
#include <cstddef>
#include <cstdint>

// EdgeNet bf16-MFMA pipeline, round 9b (compile fix of r9):
//   AB[n] precomputed per node (A = x@W0i^T - pos@W0e^T + b0 | B = x@W0j^T + pos@W0e^T)
//   Edge kernel: NON-persistent 12500 blocks x 512 thr (8 waves), BM=64.
//    - HSTR = 264 (u16): HSTR/8 = 33 ODD -> row*33 mod 8 bijective -> ALL LDS
//      access patterns uniform across bank groups. No XOR swizzle.
//    - Non-temporal out stores (via ext_vector f32x4, not HIP float4) to stop
//      the 400MB write stream from evicting the 51MB AB table out of L2/L3.

#define N_NODES_C 50000
#define N_EDGES_C 800000
#define D_FEAT_C  128
#define IN_CH_C   259
#define HID_C     256
#define OUT_CH_C  128

#define BM9    64
#define HSTR9  264                   // u16 row stride; 264/8=33 odd -> uniform banks

typedef unsigned short u16;
typedef short bf16x8 __attribute__((ext_vector_type(8)));
typedef float f32x4 __attribute__((ext_vector_type(4)));

__device__ __forceinline__ u16 f2bf(float f) {
    union { float f; unsigned u; } v; v.f = f;
    unsigned u = v.u;
    return (u16)((u + 0x7fffu + ((u >> 16) & 1u)) >> 16);   // RNE
}
__device__ __forceinline__ unsigned cvt_pk_bf16(float lo, float hi) {
    unsigned r;
    asm("v_cvt_pk_bf16_f32 %0, %1, %2" : "=v"(r) : "v"(lo), "v"(hi));
    return r;
}
__device__ __forceinline__ float bf2f_lo(unsigned u) {
    union { unsigned u; float f; } v; v.u = u << 16; return v.f;
}
__device__ __forceinline__ float bf2f_hi(unsigned u) {
    union { unsigned u; float f; } v; v.u = u & 0xFFFF0000u; return v.f;
}
__device__ __forceinline__ float elu1(float x) {
    return x > 0.0f ? x : (__expf(x) - 1.0f);
}
__device__ __forceinline__ unsigned addelu_pk(unsigned a, unsigned b) {
    float s0 = elu1(bf2f_lo(a) + bf2f_lo(b));
    float s1 = elu1(bf2f_hi(a) + bf2f_hi(b));
    return cvt_pk_bf16(s0, s1);
}

__global__ void detect_idx64(const void* __restrict__ ei_raw, int* __restrict__ flag) {
    if (blockIdx.x == 0 && threadIdx.x == 0) {
        const unsigned long long* p = (const unsigned long long*)ei_raw;
        int is64 = 1;
        for (int i = 0; i < 64; ++i)
            if (p[i] >= (1ULL << 32)) { is64 = 0; break; }
        *flag = is64;
    }
}

// WAB[512][160] (row-major, for node_gemm) +
// W2f: fragment order [jb 16][kk 8][lane 64][8]: W2[jb*16+(l&15)][kk*32+((l>>4)<<3)+c]
// W3f: fragment order [ob  8][kk 8][lane 64][8]: W3[ob*16+(l&15)][kk*32+((l>>4)<<3)+c]
__global__ void prep_weights(const float* __restrict__ W0, const float* __restrict__ W2,
                             const float* __restrict__ W3, u16* __restrict__ WAB,
                             u16* __restrict__ W2f, u16* __restrict__ W3f) {
    int i = blockIdx.x * blockDim.x + threadIdx.x;
    const int nwab = 512 * 160, nw2 = 256 * 256, nw3 = 128 * 256;
    if (i < nwab) {
        int j = i / 160, k = i - j * 160;
        float v = 0.f;
        if (j < 256) {                       // A-weights (src role)
            if (k < 128) v = W0[j * IN_CH_C + 3 + k];
            else if (k < 131) v = -W0[j * IN_CH_C + (k - 128)];
        } else {                             // B-weights (dst role)
            int j2 = j - 256;
            if (k < 128) v = W0[j2 * IN_CH_C + 131 + k];
            else if (k < 131) v = W0[j2 * IN_CH_C + (k - 128)];
        }
        WAB[i] = f2bf(v);
    } else if (i < nwab + nw2) {
        int q = i - nwab;
        int c = q & 7, lIdx = (q >> 3) & 63, kk = (q >> 9) & 7, jb = q >> 12;
        int j = jb * 16 + (lIdx & 15);
        int k = kk * 32 + ((lIdx >> 4) << 3) + c;
        W2f[q] = f2bf(W2[j * 256 + k]);
    } else if (i < nwab + nw2 + nw3) {
        int q = i - nwab - nw2;
        int c = q & 7, lIdx = (q >> 3) & 63, kk = (q >> 9) & 7, ob = q >> 12;
        int o = ob * 16 + (lIdx & 15);
        int k = kk * 32 + ((lIdx >> 4) << 3) + c;
        W3f[q] = f2bf(W3[o * 256 + k]);
    }
}

// AB[n][0..255] = A[n] (+b0), AB[n][256..511] = B[n].  M=50000, N=512, K=160.
extern "C" __global__ void __launch_bounds__(512, 2)
node_gemm(const float* __restrict__ x, const float* __restrict__ pos,
          const u16* __restrict__ WAB, const float* __restrict__ b0,
          u16* __restrict__ AB) {
    __shared__ u16 tile[128 * 168];
    const int t = threadIdx.x;
    const int row0 = blockIdx.x * 128;
    for (int idx = t; idx < 128 * 80; idx += 512) {
        int m = idx / 80, wq = idx - m * 80;
        int k = wq * 2, n = row0 + m;
        float f0 = 0.f, f1 = 0.f;
        if (n < N_NODES_C) {
            f0 = (k < 128) ? x[(size_t)n * 128 + k] : (k < 131 ? pos[(size_t)n * 3 + k - 128] : 0.f);
            int k1 = k + 1;
            f1 = (k1 < 128) ? x[(size_t)n * 128 + k1] : (k1 < 131 ? pos[(size_t)n * 3 + k1 - 128] : 0.f);
        }
        *(unsigned*)&tile[m * 168 + k] = (unsigned)f2bf(f0) | ((unsigned)f2bf(f1) << 16);
    }
    __syncthreads();
    const int w = t >> 6, l = t & 63, lr = l & 15, hi = l >> 4;
    for (int mc = 0; mc < 2; ++mc) {
        f32x4 acc[4][4];
#pragma unroll
        for (int ji = 0; ji < 4; ++ji)
#pragma unroll
            for (int mi = 0; mi < 4; ++mi)
                acc[ji][mi] = (f32x4){0.f, 0.f, 0.f, 0.f};
#pragma unroll
        for (int kk = 0; kk < 5; ++kk) {
            bf16x8 af[4], bfr[4];
#pragma unroll
            for (int ji = 0; ji < 4; ++ji)
                af[ji] = *(const bf16x8*)&WAB[(size_t)(w * 64 + ji * 16 + lr) * 160 + kk * 32 + hi * 8];
#pragma unroll
            for (int mi = 0; mi < 4; ++mi)
                bfr[mi] = *(const bf16x8*)&tile[(mc * 64 + mi * 16 + lr) * 168 + kk * 32 + hi * 8];
#pragma unroll
            for (int ji = 0; ji < 4; ++ji)
#pragma unroll
                for (int mi = 0; mi < 4; ++mi)
                    acc[ji][mi] = __builtin_amdgcn_mfma_f32_16x16x32_bf16(af[ji], bfr[mi], acc[ji][mi], 0, 0, 0);
        }
#pragma unroll
        for (int ji = 0; ji < 4; ++ji) {
            int j0 = w * 64 + ji * 16 + hi * 4;
            float4 bb = make_float4(0.f, 0.f, 0.f, 0.f);
            if (j0 < 256) bb = *(const float4*)&b0[j0];
#pragma unroll
            for (int mi = 0; mi < 4; ++mi) {
                int nn = row0 + mc * 64 + mi * 16 + lr;
                if (nn < N_NODES_C) {
                    f32x4 v = acc[ji][mi];
                    uint2 pr;
                    pr.x = cvt_pk_bf16(v[0] + bb.x, v[1] + bb.y);
                    pr.y = cvt_pk_bf16(v[2] + bb.z, v[3] + bb.w);
                    *(uint2*)&AB[(size_t)nn * 512 + j0] = pr;
                }
            }
        }
    }
}

// Edge kernel round 9: 64 edges/block, 8 waves, odd-stride LDS, nt out stores.
extern "C" __global__ void __launch_bounds__(512, 4)
edge_mlp_v9(const u16* __restrict__ AB, const void* __restrict__ ei_raw,
            const int* __restrict__ idx64_flag,
            const u16* __restrict__ W2f, const float* __restrict__ b2,
            const u16* __restrict__ W3f, const float* __restrict__ b3,
            float* __restrict__ out) {
    __shared__ u16 h1[BM9 * HSTR9];          // 33.8 KB
    __shared__ u16 h2[BM9 * HSTR9];          // 33.8 KB

    const int t = threadIdx.x;
    const int e0 = blockIdx.x * BM9;
    const int w = t >> 6, l = t & 63, lr = l & 15, hi = l >> 4;

    // ---- phase 0: gather + h1 = elu(A[src] + B[dst]) ----
    // thread t: edge m = t>>3, 64B chunk q = t&7 (32 u16 of A + 32 of B)
    {
        const int m = t >> 3, q = t & 7;
        const int eid = e0 + m;
        int sA, sB;
        if (*idx64_flag) {
            const long long* e = (const long long*)ei_raw;
            sA = (int)e[eid]; sB = (int)e[N_EDGES_C + eid];
        } else {
            const int* e = (const int*)ei_raw;
            sA = e[eid]; sB = e[N_EDGES_C + eid];
        }
        const u16* ra = AB + (size_t)sA * 512 + q * 32;
        const u16* rb = AB + (size_t)sB * 512 + 256 + q * 32;
        uint4 a[4], b[4];
#pragma unroll
        for (int i = 0; i < 4; ++i) a[i] = *(const uint4*)(ra + i * 8);
#pragma unroll
        for (int i = 0; i < 4; ++i) b[i] = *(const uint4*)(rb + i * 8);
#pragma unroll
        for (int i = 0; i < 4; ++i) {
            uint4 r;
            r.x = addelu_pk(a[i].x, b[i].x);
            r.y = addelu_pk(a[i].y, b[i].y);
            r.z = addelu_pk(a[i].z, b[i].z);
            r.w = addelu_pk(a[i].w, b[i].w);
            *(uint4*)&h1[m * HSTR9 + q * 32 + i * 8] = r;
        }
    }
    __syncthreads();                                      // B1: h1 ready

    // ---- layer 1 (swapped): D[j][m] = W2[j][:] . h1[m][:] + b2 ----
    // wave w owns j-block w*32 (ji 0..1) x all m (mi 0..3) -> dup-free
    f32x4 acc[2][4];
#pragma unroll
    for (int ji = 0; ji < 2; ++ji) {
        const float4 bb = *(const float4*)&b2[w * 32 + ji * 16 + hi * 4];
#pragma unroll
        for (int mi = 0; mi < 4; ++mi)
            acc[ji][mi] = (f32x4){bb.x, bb.y, bb.z, bb.w};
    }
    __builtin_amdgcn_s_setprio(1);
#pragma unroll
    for (int kk = 0; kk < 8; ++kk) {
        bf16x8 af[2], bfr[4];
#pragma unroll
        for (int ji = 0; ji < 2; ++ji)                     // coalesced 1KB fragment loads
            af[ji] = *(const bf16x8*)&W2f[(size_t)(((w * 2 + ji) * 8 + kk) * 64 + l) * 8];
#pragma unroll
        for (int mi = 0; mi < 4; ++mi) {
            int row = mi * 16 + lr;
            bfr[mi] = *(const bf16x8*)&h1[row * HSTR9 + kk * 32 + hi * 8];
        }
#pragma unroll
        for (int ji = 0; ji < 2; ++ji)
#pragma unroll
            for (int mi = 0; mi < 4; ++mi)
                acc[ji][mi] = __builtin_amdgcn_mfma_f32_16x16x32_bf16(af[ji], bfr[mi], acc[ji][mi], 0, 0, 0);
    }
    __builtin_amdgcn_s_setprio(0);

    // epilogue: h2[m][j] = elu(D[j][m]); separate buffer -> no barrier needed here
#pragma unroll
    for (int ji = 0; ji < 2; ++ji) {
        int j0 = w * 32 + ji * 16 + hi * 4;
#pragma unroll
        for (int mi = 0; mi < 4; ++mi) {
            int mm = mi * 16 + lr;
            f32x4 v = acc[ji][mi];
            uint2 pr;
            pr.x = cvt_pk_bf16(elu1(v[0]), elu1(v[1]));
            pr.y = cvt_pk_bf16(elu1(v[2]), elu1(v[3]));
            *(uint2*)&h2[mm * HSTR9 + j0] = pr;
        }
    }
    __syncthreads();                                      // B2: h2 ready

    // ---- layer 2 (swapped): D[o][m] = W3[o][:] . h2[m][:] + b3 ----
    // wave w owns o-block w*16 x all m -> dup-free
    f32x4 acc2[4];                                        // [mi]; reg r -> o = w*16+hi*4+r
    {
        const float4 bv = *(const float4*)&b3[w * 16 + hi * 4];
#pragma unroll
        for (int mi = 0; mi < 4; ++mi)
            acc2[mi] = (f32x4){bv.x, bv.y, bv.z, bv.w};
    }
    __builtin_amdgcn_s_setprio(1);
#pragma unroll
    for (int kk = 0; kk < 8; ++kk) {
        bf16x8 af3, bh[4];
        af3 = *(const bf16x8*)&W3f[(size_t)((w * 8 + kk) * 64 + l) * 8];
#pragma unroll
        for (int mi = 0; mi < 4; ++mi) {
            int row = mi * 16 + lr;
            bh[mi] = *(const bf16x8*)&h2[row * HSTR9 + kk * 32 + hi * 8];
        }
#pragma unroll
        for (int mi = 0; mi < 4; ++mi)
            acc2[mi] = __builtin_amdgcn_mfma_f32_16x16x32_bf16(af3, bh[mi], acc2[mi], 0, 0, 0);
    }
    __builtin_amdgcn_s_setprio(0);

    // store (non-temporal, native ext-vector type): out[m = mi*16+lr][o = w*16+hi*4..+3]
#pragma unroll
    for (int mi = 0; mi < 4; ++mi) {
        f32x4 v = acc2[mi];
        f32x4* dst = (f32x4*)&out[(size_t)(e0 + mi * 16 + lr) * 128 + w * 16 + hi * 4];
        __builtin_nontemporal_store(v, dst);
    }
}

// ---------------- round-1 f32 fallback (ws too small) ----------------
#define BM 64
#define PAD 65
__global__ void transpose_f32(const float* __restrict__ src, float* __restrict__ dst, int R, int C) {
    int i = blockIdx.x * blockDim.x + threadIdx.x;
    if (i < R * C) { int c = i / R; int r = i - c * R; dst[i] = src[r * C + c]; }
}
__device__ __forceinline__ void layer256(const float* __restrict__ wt, const float* __restrict__ b,
                                         const float* in_lds, float* out_lds, int K, int t) {
    const int jg = t & 63, mc = t >> 6;
    const float* wp = wt + jg * 4;
    const float4 bv = *(const float4*)&b[jg * 4];
    float acc[8][4];
#pragma unroll
    for (int i = 0; i < 8; ++i) { acc[i][0] = bv.x; acc[i][1] = bv.y; acc[i][2] = bv.z; acc[i][3] = bv.w; }
    const float* hbase = in_lds + mc * 8;
    float4 wv = *(const float4*)wp;
    for (int k = 0; k < K; ++k) {
        float4 wn = wv;
        if (k + 1 < K) wn = *(const float4*)(wp + (size_t)(k + 1) * HID_C);
        float h[8];
#pragma unroll
        for (int i = 0; i < 8; ++i) h[i] = hbase[k * PAD + i];
#pragma unroll
        for (int i = 0; i < 8; ++i) {
            acc[i][0] += h[i] * wv.x; acc[i][1] += h[i] * wv.y;
            acc[i][2] += h[i] * wv.z; acc[i][3] += h[i] * wv.w;
        }
        wv = wn;
    }
#pragma unroll
    for (int i4 = 0; i4 < 4; ++i4)
#pragma unroll
        for (int i = 0; i < 8; ++i) {
            float v = acc[i][i4];
            v = v > 0.0f ? v : expm1f(v);
            out_lds[(jg * 4 + i4) * PAD + mc * 8 + i] = v;
        }
}
extern "C" __global__ void __launch_bounds__(512, 2)
edge_mlp_f32(const float* __restrict__ x, const void* __restrict__ ei_raw,
             const float* __restrict__ pos, const int* __restrict__ idx64_flag,
             const float* __restrict__ wt0, const float* __restrict__ b0,
             const float* __restrict__ wt2, const float* __restrict__ b2,
             const float* __restrict__ wt3, const float* __restrict__ b3,
             float* __restrict__ out) {
    __shared__ float buf1[IN_CH_C * PAD];
    __shared__ float buf2[HID_C * PAD];
    __shared__ int s_src[BM], s_dst[BM];
    const int t = threadIdx.x;
    const int e0 = blockIdx.x * BM;
    if (t < BM) {
        int s, d;
        if (*idx64_flag) {
            const long long* e = (const long long*)ei_raw;
            s = (int)e[e0 + t]; d = (int)e[N_EDGES_C + e0 + t];
        } else {
            const int* e = (const int*)ei_raw;
            s = e[e0 + t]; d = e[N_EDGES_C + e0 + t];
        }
        s_src[t] = s; s_dst[t] = d;
    }
    __syncthreads();
    if (t < BM) {
        const int s = s_src[t], d = s_dst[t];
#pragma unroll
        for (int i = 0; i < 3; ++i)
            buf1[i * PAD + t] = pos[d * 3 + i] - pos[s * 3 + i];
    }
    {
        const int l = t & 31, grp = t >> 5;
#pragma unroll
        for (int r = 0; r < 4; ++r) {
            const int m = grp + r * 16;
            const int s = s_src[m], d = s_dst[m];
            const float4 xi = *(const float4*)&x[(size_t)s * D_FEAT_C + l * 4];
            const float4 xj = *(const float4*)&x[(size_t)d * D_FEAT_C + l * 4];
            buf1[(3 + l * 4 + 0) * PAD + m] = xi.x; buf1[(3 + l * 4 + 1) * PAD + m] = xi.y;
            buf1[(3 + l * 4 + 2) * PAD + m] = xi.z; buf1[(3 + l * 4 + 3) * PAD + m] = xi.w;
            buf1[(131 + l * 4 + 0) * PAD + m] = xj.x; buf1[(131 + l * 4 + 1) * PAD + m] = xj.y;
            buf1[(131 + l * 4 + 2) * PAD + m] = xj.z; buf1[(131 + l * 4 + 3) * PAD + m] = xj.w;
        }
    }
    __syncthreads();
    layer256(wt0, b0, buf1, buf2, IN_CH_C, t);
    __syncthreads();
    layer256(wt2, b2, buf2, buf1, HID_C, t);
    __syncthreads();
    {
        const int jg = t & 31, mc = t >> 5;
        const float* wp = wt3 + jg * 4;
        const float4 bv = *(const float4*)&b3[jg * 4];
        float acc[4][4];
#pragma unroll
        for (int i = 0; i < 4; ++i) { acc[i][0] = bv.x; acc[i][1] = bv.y; acc[i][2] = bv.z; acc[i][3] = bv.w; }
        const float* hbase = buf1 + mc * 4;
        float4 wv = *(const float4*)wp;
        for (int k = 0; k < HID_C; ++k) {
            float4 wn = wv;
            if (k + 1 < HID_C) wn = *(const float4*)(wp + (size_t)(k + 1) * OUT_CH_C);
            float h[4];
#pragma unroll
            for (int i = 0; i < 4; ++i) h[i] = hbase[k * PAD + i];
#pragma unroll
            for (int i = 0; i < 4; ++i) {
                acc[i][0] += h[i] * wv.x; acc[i][1] += h[i] * wv.y;
                acc[i][2] += h[i] * wv.z; acc[i][3] += h[i] * wv.w;
            }
            wv = wn;
        }
#pragma unroll
        for (int i = 0; i < 4; ++i) {
            float4 o;
            o.x = acc[i][0]; o.y = acc[i][1]; o.z = acc[i][2]; o.w = acc[i][3];
            *(float4*)&out[(size_t)(e0 + mc * 4 + i) * OUT_CH_C + jg * 4] = o;
        }
    }
}

extern "C" void kernel_launch(void* const* d_in, const int* in_sizes, int n_in,
                              void* d_out, int out_size, void* d_ws, size_t ws_size,
                              hipStream_t stream) {
    const float* x   = (const float*)d_in[0];
    const void*  ei  = d_in[1];
    const float* pos = (const float*)d_in[2];
    const float* W0  = (const float*)d_in[3];
    const float* b0  = (const float*)d_in[4];
    const float* W2  = (const float*)d_in[5];
    const float* b2  = (const float*)d_in[6];
    const float* W3  = (const float*)d_in[7];
    const float* b3  = (const float*)d_in[8];
    float* out = (float*)d_out;

    const size_t need = (size_t)N_NODES_C * 512 * 2 + (size_t)512 * 160 * 2
                      + (size_t)256 * 256 * 2 + (size_t)128 * 256 * 2 + 16;
    if (ws_size >= need) {
        u16* AB  = (u16*)d_ws;                         // [50000][512]
        u16* WAB = AB + (size_t)N_NODES_C * 512;       // [512][160]
        u16* W2f = WAB + 512 * 160;                    // fragment-order [16][8][64][8]
        u16* W3f = W2f + 256 * 256;                    // fragment-order [8][8][64][8]
        int* flag = (int*)(W3f + 128 * 256);

        detect_idx64<<<1, 64, 0, stream>>>(ei, flag);
        prep_weights<<<704, 256, 0, stream>>>(W0, W2, W3, WAB, W2f, W3f);
        node_gemm<<<391, 512, 0, stream>>>(x, pos, WAB, b0, AB);
        edge_mlp_v9<<<N_EDGES_C / BM9, 512, 0, stream>>>(AB, ei, flag, W2f, b2, W3f, b3, out);
    } else {
        float* wt0 = (float*)d_ws;
        float* wt2 = wt0 + IN_CH_C * HID_C;
        float* wt3 = wt2 + HID_C * HID_C;
        int*   flag = (int*)(wt3 + HID_C * OUT_CH_C);

        detect_idx64<<<1, 64, 0, stream>>>(ei, flag);
        int n0 = HID_C * IN_CH_C;
        transpose_f32<<<(n0 + 255) / 256, 256, 0, stream>>>(W0, wt0, HID_C, IN_CH_C);
        int n2 = HID_C * HID_C;
        transpose_f32<<<(n2 + 255) / 256, 256, 0, stream>>>(W2, wt2, HID_C, HID_C);
        int n3 = OUT_CH_C * HID_C;
        transpose_f32<<<(n3 + 255) / 256, 256, 0, stream>>>(W3, wt3, OUT_CH_C, HID_C);
        edge_mlp_f32<<<N_EDGES_C / BM, 512, 0, stream>>>(
            x, ei, pos, flag, wt0, b0, wt2, b2, wt3, b3, out);
    }
}